// Round 3
// baseline (321.334 us; speedup 1.0000x reference)
//
#include <hip/hip_runtime.h>
#include <stdint.h>

// out = (adj @ (X@W + b)) / rowsum(adj)
// B=8, N=4096, C_IN=C_OUT=512, all fp32 in/out. bf16 MFMA internally.
// ws: hT bf16 [8][512][4096] (32 MiB), Wt bf16 [512][512] after.

typedef __attribute__((ext_vector_type(4))) float  f32x4;
typedef __attribute__((ext_vector_type(8))) __bf16 bf16x8;
typedef __attribute__((ext_vector_type(4))) __bf16 bf16x4;

#define GLOAD_LDS16(gsrc, ldst)                                                           \
  __builtin_amdgcn_global_load_lds((const __attribute__((address_space(1))) void*)(gsrc), \
                                   (__attribute__((address_space(3))) void*)(ldst), 16, 0, 0)

#define BARRIER                                  \
  do {                                           \
    asm volatile("" ::: "memory");               \
    __builtin_amdgcn_s_barrier();                \
    asm volatile("" ::: "memory");               \
  } while (0)

// rule 18: sched_barrier(0) right after the lgkm wait so MFMAs can't hoist above it
#define WAIT_LGKM0                                        \
  do {                                                    \
    asm volatile("s_waitcnt lgkmcnt(0)" ::: "memory");    \
    __builtin_amdgcn_sched_barrier(0);                    \
  } while (0)

// ---------------- K0: Wt[n][k] = bf16(W[k][n]), 512x512 ----------------
__global__ void __launch_bounds__(256) k_wt(const float* __restrict__ W,
                                            __bf16* __restrict__ Wt) {
  __shared__ __bf16 t[64][65];
  const int k0 = blockIdx.x * 64, n0 = blockIdx.y * 64;
  const int tid = threadIdx.x;
  const int r = tid >> 2, c4 = (tid & 3) * 16;
#pragma unroll
  for (int j = 0; j < 4; ++j) {
    f32x4 v = *reinterpret_cast<const f32x4*>(W + (size_t)(k0 + r) * 512 + n0 + c4 + j * 4);
#pragma unroll
    for (int q = 0; q < 4; ++q) t[c4 + j * 4 + q][r] = (__bf16)v[q];
  }
  __syncthreads();
#pragma unroll
  for (int j = 0; j < 4; ++j) {
    bf16x4 o;
#pragma unroll
    for (int q = 0; q < 4; ++q) o[q] = t[r][c4 + j * 4 + q];
    *reinterpret_cast<bf16x4*>(Wt + (size_t)(n0 + r) * 512 + k0 + c4 + j * 4) = o;
  }
}

// ---------------- K1: proj  h = X@W + b, stored transposed as hT[b][o][m] bf16 -----
__global__ void __launch_bounds__(256) k_proj(const float* __restrict__ X,
                                              const __bf16* __restrict__ Wt,
                                              const float* __restrict__ bias,
                                              __bf16* __restrict__ hT) {
  __shared__ __attribute__((aligned(16))) __bf16 Xs[128][72];
  __shared__ __attribute__((aligned(16))) __bf16 Ws[128][72];
  const int n0 = blockIdx.x * 128;
  const int m0 = blockIdx.y * 128;
  const int tid = threadIdx.x;
  const int lane = tid & 63, w = tid >> 6;
  const int wr = w >> 1, wc = w & 1;
  const int srow = tid >> 1, scb = (tid & 1) * 32;

  f32x4 acc[4][4] = {};

  for (int k0 = 0; k0 < 512; k0 += 64) {
    const float* xp = X + (size_t)(m0 + srow) * 512 + k0 + scb;
    f32x4 xv[8];
#pragma unroll
    for (int j = 0; j < 8; ++j) xv[j] = *reinterpret_cast<const f32x4*>(xp + j * 4);
#pragma unroll
    for (int q = 0; q < 4; ++q) {
      bf16x8 o;
#pragma unroll
      for (int e = 0; e < 8; ++e) { const int idx = q * 8 + e; o[e] = (__bf16)xv[idx >> 2][idx & 3]; }
      *reinterpret_cast<bf16x8*>(&Xs[srow][scb + q * 8]) = o;
    }
    const __bf16* wp = Wt + (size_t)(n0 + srow) * 512 + k0 + scb;
#pragma unroll
    for (int q = 0; q < 4; ++q)
      *reinterpret_cast<bf16x8*>(&Ws[srow][scb + q * 8]) =
          *reinterpret_cast<const bf16x8*>(wp + q * 8);
    __syncthreads();

    for (int kk = 0; kk < 64; kk += 32) {
      const int ko = kk + ((lane >> 4) << 3);
      bf16x8 a[4], bb[4];
#pragma unroll
      for (int i = 0; i < 4; ++i)
        a[i] = *reinterpret_cast<const bf16x8*>(&Xs[wr * 64 + i * 16 + (lane & 15)][ko]);
#pragma unroll
      for (int j = 0; j < 4; ++j)
        bb[j] = *reinterpret_cast<const bf16x8*>(&Ws[wc * 64 + j * 16 + (lane & 15)][ko]);
#pragma unroll
      for (int i = 0; i < 4; ++i)
#pragma unroll
        for (int j = 0; j < 4; ++j)
          acc[i][j] = __builtin_amdgcn_mfma_f32_16x16x32_bf16(a[i], bb[j], acc[i][j], 0, 0, 0);
    }
    __syncthreads();
  }

  float bj[4];
#pragma unroll
  for (int j = 0; j < 4; ++j) bj[j] = bias[n0 + wc * 64 + j * 16 + (lane & 15)];
  const int batch = m0 >> 12;
  const int mloc0 = (m0 & 4095) + wr * 64;
#pragma unroll
  for (int i = 0; i < 4; ++i) {
    const int m_in = mloc0 + i * 16 + ((lane >> 4) << 2);
#pragma unroll
    for (int j = 0; j < 4; ++j) {
      const int n = n0 + wc * 64 + j * 16 + (lane & 15);
      bf16x4 o;
#pragma unroll
      for (int r = 0; r < 4; ++r) o[r] = (__bf16)(acc[i][j][r] + bj[j]);
      *reinterpret_cast<bf16x4*>(hT + ((size_t)batch * 512 + n) * 4096 + m_in) = o;
    }
  }
}

// ---------------- K2: aggregation, 8-phase schedule (T2+T3+T4+T5) ----------------
// BM=128 rows x BN=512 cols (adj read once), BK=64, 64 K-tiles, 8 waves (2x4),
// wave tile 64x128. LDS: As dbuf 2x16K + Hs dbuf 2x64K = 160 KiB exactly.
// Per K-tile: 4 phases, one C-quadrant each (16 MFMA, 12 ds_read_b128), staging
// spread across phases, single vmcnt(0) at tile end (loads span ~3 phases).
__global__ void __launch_bounds__(512, 2) k_agg(const float* __restrict__ adj,
                                                const __bf16* __restrict__ hT,
                                                float* __restrict__ out) {
  __shared__ __attribute__((aligned(16))) char lds[163840];
  // As[0]=lds+0, As[1]=lds+16384, Hs[0]=lds+32768, Hs[1]=lds+98304

  const int bx = ((int)blockIdx.x & 7) * 32 + ((int)blockIdx.x >> 3);  // XCD x <-> batch x
  const int batch = bx >> 5;
  const int m0 = (bx & 31) * 128;
  const int tid = threadIdx.x;
  const int lane = tid & 63, w = tid >> 6;
  const int wr = w >> 2, wc = w & 3;  // wave tile: rows wr*64, cols wc*128

  const float*  adjb = adj + (size_t)batch * 4096 * 4096;
  const __bf16* hTb  = hT + (size_t)batch * 512 * 4096;

  // A staging (verified): thread -> row tid>>2, 16 cols from (tid&3)*16, XOR-swizzled
  const int arow = tid >> 2;
  const int acb  = (tid & 3) * 16;
  const int aswz = (arow & 7) << 4;
  const int aw0  = arow * 128 + (((acb * 2) + 0) ^ aswz);
  const int aw1  = arow * 128 + (((acb * 2) + 16) ^ aswz);
  const float* adjrow = adjb + (size_t)(m0 + arow) * 4096 + acb;

  // Hs gload source pre-swizzle (verified)
  const int srcblk = (((lane & 7) ^ ((lane >> 3) & 7)) << 3);
  const int hrow_l = (lane >> 3);

  // fragment read swizzle
  const int koffbase = (lane >> 4) << 3;
  const int kswz = (lane & 7) << 4;

  f32x4 acc[4][8] = {};
  float pdeg = 0.f;
  f32x4 av[4];

  struct Frags { bf16x8 a[2][2]; bf16x8 b[2][4]; };
  Frags f;

  auto load_adj = [&](int k0) {
#pragma unroll
    for (int j = 0; j < 4; ++j) av[j] = *reinterpret_cast<const f32x4*>(adjrow + k0 + j * 4);
  };
  auto issue_hs_half = [&](int k0, char* Hn, int half) {
#pragma unroll
    for (int q = 0; q < 4; ++q) {
      const int c = w * 8 + half * 4 + q;
      const __bf16* src = hTb + (size_t)(c * 8 + hrow_l) * 4096 + k0 + srcblk;
      GLOAD_LDS16(src, Hn + c * 1024);
    }
  };
  auto write_as = [&](char* An) {  // compiler inserts precise vmcnt for av
    bf16x8 o0, o1;
#pragma unroll
    for (int e = 0; e < 8; ++e) o0[e] = (__bf16)av[e >> 2][e & 3];
#pragma unroll
    for (int e = 0; e < 8; ++e) o1[e] = (__bf16)av[2 + (e >> 2)][e & 3];
    float s = 0.f;
#pragma unroll
    for (int e = 0; e < 16; ++e) s += av[e >> 2][e & 3];
    pdeg += s;
    *reinterpret_cast<bf16x8*>(An + aw0) = o0;
    *reinterpret_cast<bf16x8*>(An + aw1) = o1;
  };
  auto qread = [&](const char* Ac, const char* Hc, int i0, int j0) {
#pragma unroll
    for (int kk2 = 0; kk2 < 2; ++kk2) {
      const int ko2 = (((kk2 * 32) + koffbase) * 2) ^ kswz;
#pragma unroll
      for (int i = 0; i < 2; ++i) {
        const int row = wr * 64 + (i0 + i) * 16 + (lane & 15);
        f.a[kk2][i] = *reinterpret_cast<const bf16x8*>(Ac + row * 128 + ko2);
      }
#pragma unroll
      for (int j = 0; j < 4; ++j) {
        const int orow = wc * 128 + (j0 + j) * 16 + (lane & 15);
        f.b[kk2][j] = *reinterpret_cast<const bf16x8*>(Hc + orow * 128 + ko2);
      }
    }
  };
  auto qmma = [&](int i0, int j0) {
    __builtin_amdgcn_s_setprio(1);
#pragma unroll
    for (int kk2 = 0; kk2 < 2; ++kk2)
#pragma unroll
      for (int i = 0; i < 2; ++i)
#pragma unroll
        for (int j = 0; j < 4; ++j)
          acc[i0 + i][j0 + j] =
              __builtin_amdgcn_mfma_f32_16x16x32_bf16(f.a[kk2][i], f.b[kk2][j],
                                                      acc[i0 + i][j0 + j], 0, 0, 0);
    __builtin_amdgcn_s_setprio(0);
  };

  // ---- prologue: stage tile 0 into As[0]/Hs[0] ----
  load_adj(0);
  issue_hs_half(0, lds + 32768, 0);
  issue_hs_half(0, lds + 32768, 1);
  write_as(lds);
  asm volatile("s_waitcnt vmcnt(0) lgkmcnt(0)" ::: "memory");
  BARRIER;

  // ---- main loop: 4 phases per K-tile, prefetch t+1 ----
  for (int t = 0; t < 63; ++t) {
    const int cur = t & 1;
    const char* Ac = cur ? (lds + 16384) : lds;
    const char* Hc = cur ? (lds + 98304) : (lds + 32768);
    char* An = cur ? lds : (lds + 16384);
    char* Hn = cur ? (lds + 32768) : (lds + 98304);
    const int k1 = (t + 1) * 64;

    // P0: quadrant (0,0) | adj regs + Hs half 0 for t+1
    qread(Ac, Hc, 0, 0);
    load_adj(k1);
    issue_hs_half(k1, Hn, 0);
    BARRIER;
    WAIT_LGKM0;
    qmma(0, 0);
    BARRIER;

    // P1: quadrant (0,4) | Hs half 1 for t+1
    qread(Ac, Hc, 0, 4);
    issue_hs_half(k1, Hn, 1);
    BARRIER;
    WAIT_LGKM0;
    qmma(0, 4);
    BARRIER;

    // P2: quadrant (2,0) | cvt + ds_write As(t+1)  (vmcnt(8) auto for av)
    qread(Ac, Hc, 2, 0);
    write_as(An);
    BARRIER;
    WAIT_LGKM0;   // also drains own ds_writes before next barrier
    qmma(2, 0);
    BARRIER;

    // P3: quadrant (2,4) | drain Hs gloads after MFMA, then tile boundary
    qread(Ac, Hc, 2, 4);
    BARRIER;
    WAIT_LGKM0;
    qmma(2, 4);
    asm volatile("s_waitcnt vmcnt(0)" ::: "memory");
    BARRIER;
  }

  // ---- last tile (t=63, buffers idx 1), no staging ----
  {
    const char* Ac = lds + 16384;
    const char* Hc = lds + 98304;
    qread(Ac, Hc, 0, 0); WAIT_LGKM0; qmma(0, 0);
    qread(Ac, Hc, 0, 4); WAIT_LGKM0; qmma(0, 4);
    qread(Ac, Hc, 2, 0); WAIT_LGKM0; qmma(2, 0);
    qread(Ac, Hc, 2, 4); WAIT_LGKM0; qmma(2, 4);
  }

  // ---- degree: reduce 4 col-quarter partials per row, exchange via reused LDS ----
  float d = pdeg;
  d += __shfl_xor(d, 1, 64);
  d += __shfl_xor(d, 2, 64);
  BARRIER;  // all compute done; As region free for reuse
  if ((tid & 3) == 0) reinterpret_cast<float*>(lds)[arow] = d;
  __syncthreads();
  const float* degf = reinterpret_cast<const float*>(lds);

  // ---- epilogue ----
  float* outb = out + (size_t)batch * 4096 * 512;
#pragma unroll
  for (int i = 0; i < 4; ++i) {
    const int rbase = wr * 64 + i * 16 + ((lane >> 4) << 2);
    float rd[4];
#pragma unroll
    for (int r = 0; r < 4; ++r) rd[r] = 1.0f / degf[rbase + r];
#pragma unroll
    for (int j = 0; j < 8; ++j) {
      const int o = wc * 128 + j * 16 + (lane & 15);
#pragma unroll
      for (int r = 0; r < 4; ++r)
        outb[(size_t)(m0 + rbase + r) * 512 + o] = acc[i][j][r] * rd[r];
    }
  }
}

extern "C" void kernel_launch(void* const* d_in, const int* in_sizes, int n_in,
                              void* d_out, int out_size, void* d_ws, size_t ws_size,
                              hipStream_t stream) {
  (void)in_sizes; (void)n_in; (void)out_size; (void)ws_size;
  const float* X    = (const float*)d_in[0];  // [8,4096,512]
  const float* adj  = (const float*)d_in[1];  // [8,4096,4096]
  const float* W    = (const float*)d_in[2];  // [512,512]
  const float* bias = (const float*)d_in[3];  // [512]
  float* out = (float*)d_out;                 // [8,4096,512] fp32

  char* ws = (char*)d_ws;
  __bf16* hT = (__bf16*)ws;                                   // 32 MiB
  __bf16* Wt = (__bf16*)(ws + (size_t)32 * 1024 * 1024);      // 512 KiB

  k_wt<<<dim3(8, 8), 256, 0, stream>>>(W, Wt);
  k_proj<<<dim3(4, 256), 256, 0, stream>>>(X, Wt, bias, hT);
  k_agg<<<dim3(256), 512, 0, stream>>>(adj, hT, out);
}

// Round 4
// 293.833 us; speedup vs baseline: 1.0936x; 1.0936x over previous
//
#include <hip/hip_runtime.h>
#include <stdint.h>

// out = (adj @ (X@W + b)) / rowsum(adj)
// B=8, N=4096, C_IN=C_OUT=512, all fp32 in/out. bf16 MFMA internally.
// ws: hT bf16 [8][512][4096] (32 MiB), Wt bf16 [512][512] after.

typedef __attribute__((ext_vector_type(4))) float  f32x4;
typedef __attribute__((ext_vector_type(8))) __bf16 bf16x8;
typedef __attribute__((ext_vector_type(4))) __bf16 bf16x4;

#define GLOAD_LDS16(gsrc, ldst)                                                           \
  __builtin_amdgcn_global_load_lds((const __attribute__((address_space(1))) void*)(gsrc), \
                                   (__attribute__((address_space(3))) void*)(ldst), 16, 0, 0)

#define BARRIER                                  \
  do {                                           \
    asm volatile("" ::: "memory");               \
    __builtin_amdgcn_s_barrier();                \
    asm volatile("" ::: "memory");               \
  } while (0)

// ---------------- K0: Wt[n][k] = bf16(W[k][n]), 512x512 ----------------
__global__ void __launch_bounds__(256) k_wt(const float* __restrict__ W,
                                            __bf16* __restrict__ Wt) {
  __shared__ __bf16 t[64][65];
  const int k0 = blockIdx.x * 64, n0 = blockIdx.y * 64;
  const int tid = threadIdx.x;
  const int r = tid >> 2, c4 = (tid & 3) * 16;
#pragma unroll
  for (int j = 0; j < 4; ++j) {
    f32x4 v = *reinterpret_cast<const f32x4*>(W + (size_t)(k0 + r) * 512 + n0 + c4 + j * 4);
#pragma unroll
    for (int q = 0; q < 4; ++q) t[c4 + j * 4 + q][r] = (__bf16)v[q];
  }
  __syncthreads();
#pragma unroll
  for (int j = 0; j < 4; ++j) {
    bf16x4 o;
#pragma unroll
    for (int q = 0; q < 4; ++q) o[q] = t[r][c4 + j * 4 + q];
    *reinterpret_cast<bf16x4*>(Wt + (size_t)(n0 + r) * 512 + k0 + c4 + j * 4) = o;
  }
}

// ---------------- K1: proj  h = X@W + b, stored transposed as hT[b][o][m] bf16 -----
__global__ void __launch_bounds__(256) k_proj(const float* __restrict__ X,
                                              const __bf16* __restrict__ Wt,
                                              const float* __restrict__ bias,
                                              __bf16* __restrict__ hT) {
  __shared__ __attribute__((aligned(16))) __bf16 Xs[128][72];
  __shared__ __attribute__((aligned(16))) __bf16 Ws[128][72];
  const int n0 = blockIdx.x * 128;
  const int m0 = blockIdx.y * 128;
  const int tid = threadIdx.x;
  const int lane = tid & 63, w = tid >> 6;
  const int wr = w >> 1, wc = w & 1;
  const int srow = tid >> 1, scb = (tid & 1) * 32;

  f32x4 acc[4][4] = {};

  for (int k0 = 0; k0 < 512; k0 += 64) {
    const float* xp = X + (size_t)(m0 + srow) * 512 + k0 + scb;
    f32x4 xv[8];
#pragma unroll
    for (int j = 0; j < 8; ++j) xv[j] = *reinterpret_cast<const f32x4*>(xp + j * 4);
#pragma unroll
    for (int q = 0; q < 4; ++q) {
      bf16x8 o;
#pragma unroll
      for (int e = 0; e < 8; ++e) { const int idx = q * 8 + e; o[e] = (__bf16)xv[idx >> 2][idx & 3]; }
      *reinterpret_cast<bf16x8*>(&Xs[srow][scb + q * 8]) = o;
    }
    const __bf16* wp = Wt + (size_t)(n0 + srow) * 512 + k0 + scb;
#pragma unroll
    for (int q = 0; q < 4; ++q)
      *reinterpret_cast<bf16x8*>(&Ws[srow][scb + q * 8]) =
          *reinterpret_cast<const bf16x8*>(wp + q * 8);
    __syncthreads();

    for (int kk = 0; kk < 64; kk += 32) {
      const int ko = kk + ((lane >> 4) << 3);
      bf16x8 a[4], bb[4];
#pragma unroll
      for (int i = 0; i < 4; ++i)
        a[i] = *reinterpret_cast<const bf16x8*>(&Xs[wr * 64 + i * 16 + (lane & 15)][ko]);
#pragma unroll
      for (int j = 0; j < 4; ++j)
        bb[j] = *reinterpret_cast<const bf16x8*>(&Ws[wc * 64 + j * 16 + (lane & 15)][ko]);
#pragma unroll
      for (int i = 0; i < 4; ++i)
#pragma unroll
        for (int j = 0; j < 4; ++j)
          acc[i][j] = __builtin_amdgcn_mfma_f32_16x16x32_bf16(a[i], bb[j], acc[i][j], 0, 0, 0);
    }
    __syncthreads();
  }

  float bj[4];
#pragma unroll
  for (int j = 0; j < 4; ++j) bj[j] = bias[n0 + wc * 64 + j * 16 + (lane & 15)];
  const int batch = m0 >> 12;
  const int mloc0 = (m0 & 4095) + wr * 64;
#pragma unroll
  for (int i = 0; i < 4; ++i) {
    const int m_in = mloc0 + i * 16 + ((lane >> 4) << 2);
#pragma unroll
    for (int j = 0; j < 4; ++j) {
      const int n = n0 + wc * 64 + j * 16 + (lane & 15);
      bf16x4 o;
#pragma unroll
      for (int r = 0; r < 4; ++r) o[r] = (__bf16)(acc[i][j][r] + bj[j]);
      *reinterpret_cast<bf16x4*>(hT + ((size_t)batch * 512 + n) * 4096 + m_in) = o;
    }
  }
}

// ---------------- K2: aggregation, counted-vmcnt single-barrier pipeline -----------
// BM=128 x BN=512 (adj read once), BK=64, 8 waves (2x4), wave tile 64x128.
// As dbuf 2x16K + Hs dbuf 2x64K = 160 KiB, 1 block/CU.
// Per tile: issue 12 VMEM (t+1) -> vmcnt(12) [drains prior Hs gloads, never 0]
// -> lgkm(0) -> barrier -> compute -> write_as (compiler vmcnt(8) for av).
// adj loads NON-TEMPORAL (single-use; keep hT L2-resident). out stores NT.
__global__ void __launch_bounds__(512, 2) k_agg(const float* __restrict__ adj,
                                                const __bf16* __restrict__ hT,
                                                float* __restrict__ out) {
  __shared__ __attribute__((aligned(16))) char lds[163840];
  char* As0 = lds;
  char* As1 = lds + 16384;
  char* Hs0 = lds + 32768;
  char* Hs1 = lds + 98304;

  const int bx = ((int)blockIdx.x & 7) * 32 + ((int)blockIdx.x >> 3);  // XCD x <-> batch x
  const int batch = bx >> 5;
  const int m0 = (bx & 31) * 128;
  const int tid = threadIdx.x;
  const int lane = tid & 63, w = tid >> 6;
  const int wr = w >> 2, wc = w & 3;  // wave tile: rows wr*64, cols wc*128

  const float*  adjb = adj + (size_t)batch * 4096 * 4096;
  const __bf16* hTb  = hT + (size_t)batch * 512 * 4096;

  // A staging (verified): thread -> row tid>>2, 16 cols from (tid&3)*16, XOR-swizzled
  const int arow = tid >> 2;
  const int acb  = (tid & 3) * 16;
  const int aswz = (arow & 7) << 4;
  const int aw0  = arow * 128 + (((acb * 2) + 0) ^ aswz);
  const int aw1  = arow * 128 + (((acb * 2) + 16) ^ aswz);
  const float* adjrow = adjb + (size_t)(m0 + arow) * 4096 + acb;

  // Hs gload source pre-swizzle (verified)
  const int srcblk = (((lane & 7) ^ ((lane >> 3) & 7)) << 3);
  const int hrow_l = (lane >> 3);

  // fragment read swizzle
  const int koffbase = (lane >> 4) << 3;
  const int kswz = (lane & 7) << 4;

  f32x4 acc[4][8] = {};
  float pdeg = 0.f;
  f32x4 av[4];

  auto load_adj = [&](int k0) {  // non-temporal: stream-once, don't evict hT in L2
#pragma unroll
    for (int j = 0; j < 4; ++j)
      av[j] = __builtin_nontemporal_load(reinterpret_cast<const f32x4*>(adjrow + k0 + j * 4));
  };
  auto issue_hs = [&](int k0, char* Hn) {
#pragma unroll
    for (int q = 0; q < 8; ++q) {
      const int c = w * 8 + q;
      const __bf16* src = hTb + (size_t)(c * 8 + hrow_l) * 4096 + k0 + srcblk;
      GLOAD_LDS16(src, Hn + c * 1024);
    }
  };
  auto write_as = [&](char* An) {  // compiler inserts precise vmcnt(8) for av
    bf16x8 o0, o1;
#pragma unroll
    for (int e = 0; e < 8; ++e) o0[e] = (__bf16)av[e >> 2][e & 3];
#pragma unroll
    for (int e = 0; e < 8; ++e) o1[e] = (__bf16)av[2 + (e >> 2)][e & 3];
    float s = 0.f;
#pragma unroll
    for (int e = 0; e < 16; ++e) s += av[e >> 2][e & 3];
    pdeg += s;
    *reinterpret_cast<bf16x8*>(An + aw0) = o0;
    *reinterpret_cast<bf16x8*>(An + aw1) = o1;
  };
  auto compute = [&](const char* Ac, const char* Hc) {
#pragma unroll
    for (int kk = 0; kk < 64; kk += 32) {
      const int ko2 = ((kk + koffbase) * 2) ^ kswz;
      bf16x8 a[4], bb[8];
#pragma unroll
      for (int i = 0; i < 4; ++i) {
        const int row = wr * 64 + i * 16 + (lane & 15);
        a[i] = *reinterpret_cast<const bf16x8*>(Ac + row * 128 + ko2);
      }
#pragma unroll
      for (int j = 0; j < 8; ++j) {
        const int orow = wc * 128 + j * 16 + (lane & 15);
        bb[j] = *reinterpret_cast<const bf16x8*>(Hc + orow * 128 + ko2);
      }
      asm volatile("s_waitcnt lgkmcnt(0)" ::: "memory");
      __builtin_amdgcn_sched_barrier(0);  // rule 18
      __builtin_amdgcn_s_setprio(1);
#pragma unroll
      for (int i = 0; i < 4; ++i)
#pragma unroll
        for (int j = 0; j < 8; ++j)
          acc[i][j] = __builtin_amdgcn_mfma_f32_16x16x32_bf16(a[i], bb[j], acc[i][j], 0, 0, 0);
      __builtin_amdgcn_s_setprio(0);
    }
  };

  // ---- prologue: stage tile 0 ----
  load_adj(0);
  issue_hs(0, Hs0);      // 8 gloads outstanding entering the loop
  write_as(As0);         // waits av (vmcnt(8) precise), ds_writes pend

  // ---- main loop: 1 barrier per tile, counted vmcnt ----
  for (int t = 0; t < 63; ++t) {
    const int cur = t & 1;
    const char* Ac = cur ? As1 : As0;
    const char* Hc = cur ? Hs1 : Hs0;
    char* An = cur ? As0 : As1;
    char* Hn = cur ? Hs0 : Hs1;

    load_adj((t + 1) * 64);       // 4 VMEM
    issue_hs((t + 1) * 64, Hn);   // 8 VMEM  (outstanding: 8 old + 12 new)
    asm volatile("s_waitcnt vmcnt(12)" ::: "memory");  // drain ONLY prior tile's Hs gloads
    asm volatile("s_waitcnt lgkmcnt(0)" ::: "memory"); // own As(t) ds_writes drained
    BARRIER;                      // Hs[cur] + As[cur] published CU-wide
    compute(Ac, Hc);
    write_as(An);                 // av-wait = vmcnt(8); ds_writes drain at next lgkm(0)
  }

  // ---- last tile (t=63, buffers idx 1) ----
  asm volatile("s_waitcnt vmcnt(0)" ::: "memory");
  asm volatile("s_waitcnt lgkmcnt(0)" ::: "memory");
  BARRIER;
  compute(As1, Hs1);

  // ---- degree: reduce 4 col-quarter partials per row via shfl + reused LDS ----
  float d = pdeg;
  d += __shfl_xor(d, 1, 64);
  d += __shfl_xor(d, 2, 64);
  __syncthreads();  // all compute done; As region free for reuse
  if ((tid & 3) == 0) reinterpret_cast<float*>(lds)[arow] = d;
  __syncthreads();
  const float* degf = reinterpret_cast<const float*>(lds);

  // ---- epilogue: divide, NT store fp32 ----
  float* outb = out + (size_t)batch * 4096 * 512;
#pragma unroll
  for (int i = 0; i < 4; ++i) {
    const int rbase = wr * 64 + i * 16 + ((lane >> 4) << 2);
    float rd[4];
#pragma unroll
    for (int r = 0; r < 4; ++r) rd[r] = 1.0f / degf[rbase + r];
#pragma unroll
    for (int j = 0; j < 8; ++j) {
      const int o = wc * 128 + j * 16 + (lane & 15);
#pragma unroll
      for (int r = 0; r < 4; ++r)
        __builtin_nontemporal_store(acc[i][j][r] * rd[r],
                                    &outb[(size_t)(m0 + rbase + r) * 512 + o]);
    }
  }
}

extern "C" void kernel_launch(void* const* d_in, const int* in_sizes, int n_in,
                              void* d_out, int out_size, void* d_ws, size_t ws_size,
                              hipStream_t stream) {
  (void)in_sizes; (void)n_in; (void)out_size; (void)ws_size;
  const float* X    = (const float*)d_in[0];  // [8,4096,512]
  const float* adj  = (const float*)d_in[1];  // [8,4096,4096]
  const float* W    = (const float*)d_in[2];  // [512,512]
  const float* bias = (const float*)d_in[3];  // [512]
  float* out = (float*)d_out;                 // [8,4096,512] fp32

  char* ws = (char*)d_ws;
  __bf16* hT = (__bf16*)ws;                                   // 32 MiB
  __bf16* Wt = (__bf16*)(ws + (size_t)32 * 1024 * 1024);      // 512 KiB

  k_wt<<<dim3(8, 8), 256, 0, stream>>>(W, Wt);
  k_proj<<<dim3(4, 256), 256, 0, stream>>>(X, Wt, bias, hT);
  k_agg<<<dim3(256), 512, 0, stream>>>(adj, hT, out);
}